// Round 7
// baseline (854.891 us; speedup 1.0000x reference)
//
#include <hip/hip_runtime.h>
#include <cstdint>
#include <cstddef>

#define D 64
#define SMAX 24

typedef __attribute__((ext_vector_type(8))) short short8;
typedef __attribute__((ext_vector_type(4))) float floatx4;

__device__ inline unsigned short f2bf(float f) {   // RNE fp32 -> bf16
    unsigned u = __float_as_uint(f);
    unsigned r = 0x7FFFu + ((u >> 16) & 1u);
    return (unsigned short)((u + r) >> 16);
}
__device__ inline float bf2f(unsigned short h) {
    return __uint_as_float(((unsigned)h) << 16);
}

// ---------------- bucket-partition CSR build ----------------

__global__ void k_hist(const int* __restrict__ col, int* __restrict__ ghist,
                       int E, int NBK) {
    extern __shared__ int lh[];
    int t = threadIdx.x;
    for (int i = t; i < NBK; i += 256) lh[i] = 0;
    __syncthreads();
    int base = blockIdx.x * 8192;
    int end = base + 8192; if (end > E) end = E;
    for (int e = base + t; e < end; e += 256) atomicAdd(&lh[col[e] >> 8], 1);
    __syncthreads();
    for (int i = t; i < NBK; i += 256) if (lh[i]) atomicAdd(&ghist[i], lh[i]);
}

__global__ void k_bscan(const int* __restrict__ ghist, int* __restrict__ bstart,
                        int* __restrict__ gcur, int* __restrict__ offs,
                        int NBK, int N, int E) {
    __shared__ int s[512];
    int t = threadIdx.x;
    int v = (t < NBK) ? ghist[t] : 0;
    s[t] = v; __syncthreads();
    for (int off = 1; off < 512; off <<= 1) {
        int x = (t >= off) ? s[t - off] : 0;
        __syncthreads();
        s[t] += x;
        __syncthreads();
    }
    int excl = s[t] - v;
    if (t < NBK) { bstart[t] = excl; gcur[t] = excl; }
    if (t == 0) { bstart[NBK] = E; offs[N] = E; }
}

__global__ __launch_bounds__(256) void k_part(const int* __restrict__ row,
                                              const int* __restrict__ col,
                                              int* __restrict__ gcur,
                                              int2* __restrict__ part,
                                              int E, int NBK) {
    extern __shared__ int sm[];
    int* lcnt = sm;
    int* lbase = sm + NBK;
    int t = threadIdx.x;
    for (int i = t; i < NBK; i += 256) lcnt[i] = 0;
    __syncthreads();
    int base = blockIdx.x * 8192;
    int end = base + 8192; if (end > E) end = E;
    for (int e = base + t; e < end; e += 256) atomicAdd(&lcnt[col[e] >> 8], 1);
    __syncthreads();
    for (int i = t; i < NBK; i += 256) {
        int c = lcnt[i];
        lbase[i] = c ? atomicAdd(&gcur[i], c) : 0;
    }
    __syncthreads();
    for (int i = t; i < NBK; i += 256) lcnt[i] = 0;
    __syncthreads();
    for (int e = base + t; e < end; e += 256) {
        int c = col[e];
        int b = c >> 8;
        int p = lbase[b] + atomicAdd(&lcnt[b], 1);
        part[p] = make_int2(row[e], c);
    }
}

__global__ __launch_bounds__(256) void k_bucket(const int2* __restrict__ part,
                                                const int* __restrict__ bstart,
                                                int* __restrict__ offs,
                                                float* __restrict__ dis,
                                                int* __restrict__ csrc, int N) {
    __shared__ int ncnt[256];
    __shared__ int s[256];
    __shared__ int lcur[256];
    int b = blockIdx.x;
    int t = threadIdx.x;
    int n0 = b << 8;
    int e0 = bstart[b], e1 = bstart[b + 1];
    ncnt[t] = 0;
    __syncthreads();
    for (int e = e0 + t; e < e1; e += 256) {
        int2 pr = part[e];
        atomicAdd(&ncnt[pr.y & 255], 1);
    }
    __syncthreads();
    int v = ncnt[t];
    s[t] = v; __syncthreads();
    for (int off = 1; off < 256; off <<= 1) {
        int x = (t >= off) ? s[t - off] : 0;
        __syncthreads();
        s[t] += x;
        __syncthreads();
    }
    int excl = s[t] - v;
    int node = n0 + t;
    if (node < N) {
        offs[node] = e0 + excl;
        dis[node] = rsqrtf((float)(v + 1));
    }
    lcur[t] = excl;
    __syncthreads();
    for (int e = e0 + t; e < e1; e += 256) {
        int2 pr = part[e];
        int p = atomicAdd(&lcur[pr.y & 255], 1);
        csrc[e0 + p] = pr.x;
    }
}

// graph boundaries
__global__ void k_gb(const int* __restrict__ batch, int* __restrict__ gstart,
                     int N, int G) {
    int g = threadIdx.x;
    if (g > G) return;
    int lo = 0, hi = N;
    while (lo < hi) {
        int mid = (lo + hi) >> 1;
        if (batch[mid] < g) lo = mid + 1; else hi = mid;
    }
    gstart[g] = lo;
}

// fold BN (eval) + conv bias into per-channel scale/shift
__global__ void k_bnprep(const float* __restrict__ cb, const float* __restrict__ g,
                         const float* __restrict__ be, const float* __restrict__ mu,
                         const float* __restrict__ var, float* __restrict__ sc,
                         float* __restrict__ sh, int LD) {
    int i = blockIdx.x * 256 + threadIdx.x;
    if (i < LD) {
        float s = g[i] * rsqrtf(var[i] + 1e-5f);
        sc[i] = s;
        sh[i] = (cb[i] - mu[i]) * s + be[i];
    }
}

// split fp32 weights into bf16 hi/lo, stored TRANSPOSED [n][k]
__global__ void k_wsplit(const float* __restrict__ B, unsigned short* __restrict__ hiT,
                         unsigned short* __restrict__ loT, int K, int Nc, int nshift) {
    int idx = blockIdx.x * 256 + threadIdx.x;
    if (idx >= K * Nc) return;
    int k = idx >> nshift;
    int n = idx & (Nc - 1);
    float a = B[idx];
    unsigned b = __float_as_uint(a);
    unsigned hb = b & 0xFFFF0000u;
    float ah = __uint_as_float(hb);
    float al = a - ah;
    hiT[(size_t)n * K + k] = (unsigned short)(hb >> 16);
    loT[(size_t)n * K + k] = (unsigned short)(__float_as_uint(al) >> 16);
}

// ---------------- conv GEMM: xw' = bf16((A @ W) * dis[row]),  K=D=64 ----------------

__global__ __launch_bounds__(256) void k_conv(const float* __restrict__ A, int lda,
                                              const float* __restrict__ W,
                                              const float* __restrict__ dis,
                                              unsigned short* __restrict__ out, int N) {
    __shared__ float At[64][68];
    __shared__ float Wl[64][64];
    int t = threadIdx.x;
    int bm = blockIdx.x * 64;
    {
        int row = t >> 2, kc = (t & 3) * 16;
        int r = bm + row;
        float v[16];
        if (r < N) {
            const float* p = A + (size_t)r * lda + kc;
#pragma unroll
            for (int j = 0; j < 16; j += 4) {
                float4 x = *(const float4*)(p + j);
                v[j] = x.x; v[j + 1] = x.y; v[j + 2] = x.z; v[j + 3] = x.w;
            }
        } else {
#pragma unroll
            for (int j = 0; j < 16; ++j) v[j] = 0.f;
        }
#pragma unroll
        for (int j = 0; j < 16; ++j) At[kc + j][row] = v[j];
        const float* wp = W + row * 64 + kc;
#pragma unroll
        for (int j = 0; j < 16; j += 4)
            *(float4*)&Wl[row][kc + j] = *(const float4*)(wp + j);
    }
    __syncthreads();
    int m0 = (t & 15) * 4, n0 = (t >> 4) * 4;
    float acc[4][4];
#pragma unroll
    for (int i = 0; i < 4; ++i)
#pragma unroll
        for (int j = 0; j < 4; ++j) acc[i][j] = 0.f;
#pragma unroll 8
    for (int kk = 0; kk < 64; ++kk) {
        float4 a = *(const float4*)&At[kk][m0];
        float4 b = *(const float4*)&Wl[kk][n0];
        float av[4] = {a.x, a.y, a.z, a.w};
        float bv[4] = {b.x, b.y, b.z, b.w};
#pragma unroll
        for (int i = 0; i < 4; ++i)
#pragma unroll
            for (int j = 0; j < 4; ++j) acc[i][j] = fmaf(av[i], bv[j], acc[i][j]);
    }
#pragma unroll
    for (int i = 0; i < 4; ++i) {
        int r = bm + m0 + i;
        if (r < N) {
            float dv = dis[r];
            ushort4 o;
            o.x = f2bf(acc[i][0] * dv);
            o.y = f2bf(acc[i][1] * dv);
            o.z = f2bf(acc[i][2] * dv);
            o.w = f2bf(acc[i][3] * dv);
            *(ushort4*)&out[(size_t)r * 64 + n0] = o;
        }
    }
}

// ---------------- aggregation: one node per wave, bf16 gathers; writes fp32 + bf16 ----------------

__global__ __launch_bounds__(256) void k_agg(const unsigned short* __restrict__ xw,
                                             const int* __restrict__ offs,
                                             const int* __restrict__ src,
                                             const float* __restrict__ dis,
                                             const float* __restrict__ sc,
                                             const float* __restrict__ sh,
                                             const float* __restrict__ skip,
                                             float* __restrict__ out,
                                             int ld,
                                             unsigned short* __restrict__ outb,
                                             int N) {
    int t = threadIdx.x;
    int lane = t & 63;
    int w = t >> 6;
    int v = blockIdx.x * 4 + w;
    if (v >= N) return;
    int es = lane >> 4;         // edge slot 0..3
    int f4 = lane & 15;         // 4-channel group
    int c0 = f4 * 4;
    const unsigned short* xp = xw + c0;
    float ax = 0.f, ay = 0.f, az = 0.f, aw_ = 0.f;
    int e0 = offs[v], e1 = offs[v + 1];
    int deg = e1 - e0;
    int k = 0;
    for (; k + 16 <= deg; k += 16) {
        int ld16 = (lane < 16) ? src[e0 + k + lane] : 0;
        int s0 = __shfl(ld16, es);
        int s1 = __shfl(ld16, es + 4);
        int s2 = __shfl(ld16, es + 8);
        int s3 = __shfl(ld16, es + 12);
        ushort4 m0 = *(const ushort4*)(xp + (size_t)s0 * 64);
        ushort4 m1 = *(const ushort4*)(xp + (size_t)s1 * 64);
        ushort4 m2 = *(const ushort4*)(xp + (size_t)s2 * 64);
        ushort4 m3 = *(const ushort4*)(xp + (size_t)s3 * 64);
        ax += (bf2f(m0.x) + bf2f(m1.x)) + (bf2f(m2.x) + bf2f(m3.x));
        ay += (bf2f(m0.y) + bf2f(m1.y)) + (bf2f(m2.y) + bf2f(m3.y));
        az += (bf2f(m0.z) + bf2f(m1.z)) + (bf2f(m2.z) + bf2f(m3.z));
        aw_ += (bf2f(m0.w) + bf2f(m1.w)) + (bf2f(m2.w) + bf2f(m3.w));
    }
    for (; k + 4 <= deg; k += 4) {
        int ld4 = (lane < 4) ? src[e0 + k + lane] : 0;
        int s0 = __shfl(ld4, es);
        ushort4 m0 = *(const ushort4*)(xp + (size_t)s0 * 64);
        ax += bf2f(m0.x); ay += bf2f(m0.y); az += bf2f(m0.z); aw_ += bf2f(m0.w);
    }
    int rem = deg - k;
    if (es < rem) {
        int s0 = src[e0 + k + es];
        ushort4 m0 = *(const ushort4*)(xp + (size_t)s0 * 64);
        ax += bf2f(m0.x); ay += bf2f(m0.y); az += bf2f(m0.z); aw_ += bf2f(m0.w);
    }
    ax += __shfl_xor(ax, 16); ay += __shfl_xor(ay, 16);
    az += __shfl_xor(az, 16); aw_ += __shfl_xor(aw_, 16);
    ax += __shfl_xor(ax, 32); ay += __shfl_xor(ay, 32);
    az += __shfl_xor(az, 32); aw_ += __shfl_xor(aw_, 32);
    if (es == 0) {
        ushort4 a = *(const ushort4*)(xp + (size_t)v * 64);   // self loop
        ax += bf2f(a.x); ay += bf2f(a.y); az += bf2f(a.z); aw_ += bf2f(a.w);
        float dv = dis[v];
        float4 S = *(const float4*)&sc[c0];
        float4 H = *(const float4*)&sh[c0];
        float y0 = fmaxf(fmaf(ax * dv, S.x, H.x), 0.f);
        float y1 = fmaxf(fmaf(ay * dv, S.y, H.y), 0.f);
        float y2 = fmaxf(fmaf(az * dv, S.z, H.z), 0.f);
        float y3 = fmaxf(fmaf(aw_ * dv, S.w, H.w), 0.f);
        size_t ob = (size_t)v * ld + c0;
        if (skip) {
            const float4 s4 = *(const float4*)(skip + ob);
            y0 += s4.x; y1 += s4.y; y2 += s4.z; y3 += s4.w;
        }
        float4 o; o.x = y0; o.y = y1; o.z = y2; o.w = y3;
        *(float4*)(out + ob) = o;
        ushort4 ob4;
        ob4.x = f2bf(y0); ob4.y = f2bf(y1); ob4.z = f2bf(y2); ob4.w = f2bf(y3);
        *(ushort4*)(outb + ob) = ob4;   // same layout, bf16 plane (outb row stride == ld)
    }
}

// ---------------- encoder GEMM: barrier-free, A bf16 direct-from-global ----------------
// C = relu(A @ (Bhi+Blo) + bias). Wave tile: m=32 (2 frags) x n=64 (4 frags).
// WN waves across n; block = 4 waves; BM = 32*(4/WN). No LDS, no __syncthreads.

__global__ __launch_bounds__(256) void k_encb(const unsigned short* __restrict__ A,
                                              int M, int K, int WN,
                                              const unsigned short* __restrict__ BhiT,
                                              const unsigned short* __restrict__ BloT,
                                              const float* __restrict__ bias,
                                              unsigned short* __restrict__ Cb,
                                              float* __restrict__ Cf, int ldc) {
    int t = threadIdx.x;
    int lane = t & 63;
    int l16 = lane & 15;
    int quad = lane >> 4;
    int w = t >> 6;
    int nw = w % WN;
    int mg = w / WN;
    int BM = 32 * (4 / WN);
    int bm = blockIdx.x * BM + mg * 32;
    int n0 = nw * 64;

    floatx4 acc[2][4];
#pragma unroll
    for (int i = 0; i < 2; ++i)
#pragma unroll
        for (int j = 0; j < 4; ++j) acc[i][j] = (floatx4)0.f;

    int m0 = bm + l16, m1 = bm + 16 + l16;
    bool v0 = m0 < M, v1 = m1 < M;
    const unsigned short* a0 = A + (size_t)(v0 ? m0 : 0) * K + quad * 8;
    const unsigned short* a1 = A + (size_t)(v1 ? m1 : 0) * K + quad * 8;
    const unsigned short* bp[4];
#pragma unroll
    for (int j = 0; j < 4; ++j)
        bp[j] = BhiT + (size_t)(n0 + j * 16 + l16) * K + quad * 8;
    size_t loOff = (size_t)(BloT - BhiT);

#pragma unroll 4
    for (int k0 = 0; k0 < K; k0 += 32) {
        short8 av0 = *(const short8*)(a0 + k0);
        short8 av1 = *(const short8*)(a1 + k0);
        short8 bh[4], bl[4];
#pragma unroll
        for (int j = 0; j < 4; ++j) {
            bh[j] = *(const short8*)(bp[j] + k0);
            bl[j] = *(const short8*)(bp[j] + loOff + k0);
        }
#pragma unroll
        for (int j = 0; j < 4; ++j) {
            acc[0][j] = __builtin_amdgcn_mfma_f32_16x16x32_bf16(av0, bl[j], acc[0][j], 0, 0, 0);
            acc[0][j] = __builtin_amdgcn_mfma_f32_16x16x32_bf16(av0, bh[j], acc[0][j], 0, 0, 0);
            acc[1][j] = __builtin_amdgcn_mfma_f32_16x16x32_bf16(av1, bl[j], acc[1][j], 0, 0, 0);
            acc[1][j] = __builtin_amdgcn_mfma_f32_16x16x32_bf16(av1, bh[j], acc[1][j], 0, 0, 0);
        }
    }

#pragma unroll
    for (int i = 0; i < 2; ++i) {
#pragma unroll
        for (int r = 0; r < 4; ++r) {
            int m = bm + i * 16 + quad * 4 + r;
            if (m < M) {
#pragma unroll
                for (int j = 0; j < 4; ++j) {
                    float y = fmaxf(acc[i][j][r] + bias[n0 + j * 16 + l16], 0.f);
                    size_t idx = (size_t)m * ldc + n0 + j * 16 + l16;
                    if (Cb) Cb[idx] = f2bf(y);
                    else    Cf[idx] = y;
                }
            }
        }
    }
}

// ---------------- graph mean-pool ----------------

__global__ __launch_bounds__(256) void k_pool(const float* __restrict__ h2,
                                              const int* __restrict__ gstart,
                                              float* __restrict__ gsum, int H) {
    int g = blockIdx.x / SMAX;
    int s = blockIdx.x % SMAX;
    int base = gstart[g], end = gstart[g + 1];
    int cnt = end - base;
    if (cnt <= 0) return;
    int per = (cnt + SMAX - 1) / SMAX;
    int n0 = base + s * per;
    int n1 = n0 + per; if (n1 > end) n1 = end;
    if (n0 >= n1) return;
    int t = threadIdx.x;
    int q = t & 31;
    int c = q * 4;
    int sub = t >> 5;
    float4 acc = make_float4(0.f, 0.f, 0.f, 0.f);
    for (int n = n0 + sub; n < n1; n += 8) {
        float4 v = *(const float4*)(h2 + (size_t)n * H + c);
        acc.x += v.x; acc.y += v.y; acc.z += v.z; acc.w += v.w;
    }
    __shared__ float4 red[8][32];
    red[sub][q] = acc;
    __syncthreads();
    if (sub == 0) {
        float4 a = red[0][q];
#pragma unroll
        for (int i = 1; i < 8; ++i) {
            float4 b = red[i][q];
            a.x += b.x; a.y += b.y; a.z += b.z; a.w += b.w;
        }
        atomicAdd(&gsum[(size_t)g * H + c + 0], a.x);
        atomicAdd(&gsum[(size_t)g * H + c + 1], a.y);
        atomicAdd(&gsum[(size_t)g * H + c + 2], a.z);
        atomicAdd(&gsum[(size_t)g * H + c + 3], a.w);
    }
}

// ---------------- decoder ----------------

__global__ void k_dec(const float* __restrict__ gsum, const int* __restrict__ gstart,
                      const float* __restrict__ W1, const float* __restrict__ b1,
                      const float* __restrict__ W2, const float* __restrict__ b2,
                      float* __restrict__ out, int H, int HD) {
    int g = blockIdx.x;
    int t = threadIdx.x;
    float cnt = (float)(gstart[g + 1] - gstart[g]);
    float inv = 1.0f / fmaxf(cnt, 1.0f);
    float hid = b1[t];
    for (int k = 0; k < H; ++k) {
        float gf = gsum[(size_t)g * H + k] * inv;
        hid = fmaf(gf, W1[k * HD + t], hid);
    }
    hid = fmaxf(hid, 0.f);
    float p = hid * W2[t];
    for (int off = 32; off > 0; off >>= 1) p += __shfl_down(p, off);
    if (t == 0) out[g] = p + b2[0];
}

// ---------------- host ----------------

extern "C" void kernel_launch(void* const* d_in, const int* in_sizes, int n_in,
                              void* d_out, int out_size, void* d_ws, size_t ws_size,
                              hipStream_t stream) {
    const float* x     = (const float*)d_in[0];
    const int*   ei    = (const int*)d_in[1];
    const int*   batch = (const int*)d_in[2];
    const float* convW = (const float*)d_in[3];
    const float* convb = (const float*)d_in[4];
    const float* gamma = (const float*)d_in[5];
    const float* beta  = (const float*)d_in[6];
    const float* mean  = (const float*)d_in[7];
    const float* var   = (const float*)d_in[8];
    const float* eW1   = (const float*)d_in[9];
    const float* eb1   = (const float*)d_in[10];
    const float* eW2   = (const float*)d_in[11];
    const float* eb2   = (const float*)d_in[12];
    const float* dW1   = (const float*)d_in[13];
    const float* db1   = (const float*)d_in[14];
    const float* dW2   = (const float*)d_in[15];
    const float* db2   = (const float*)d_in[16];

    int N  = in_sizes[0] / D;
    int E  = in_sizes[1] / 2;
    int L  = in_sizes[3] / (D * D);
    int G  = out_size;
    int LD = L * D;                 // 256
    int H1 = in_sizes[10];          // 256
    int H2 = in_sizes[12];          // 128
    int HD = in_sizes[14];          // 64
    int NBK = (N + 255) >> 8;       // 391

    char* ws = (char*)d_ws;
    size_t off = 0;
    auto alloc = [&](size_t b) -> void* {
        void* p = ws + off;
        off += (b + 255) & ~(size_t)255;
        return p;
    };
    float* local  = (float*)alloc((size_t)N * LD * 4);        // fp32 layer outputs; later h2
    unsigned short* localb = (unsigned short*)alloc((size_t)N * LD * 2);  // bf16 encoder-A copy
    char*  bufB   = (char*)alloc((size_t)N * LD * 2);         // part(25.6MB)/xw(12.8MB)/h1b(51.2MB)
    int*   csrc   = (int*)alloc((size_t)E * 4);
    float* dis    = (float*)alloc((size_t)N * 4);
    int*   offs   = (int*)alloc((size_t)(N + 1) * 4);
    int*   ghist  = (int*)alloc((size_t)NBK * 4);
    int*   bstart = (int*)alloc((size_t)(NBK + 1) * 4);
    int*   gcur   = (int*)alloc((size_t)NBK * 4);
    float* sc     = (float*)alloc((size_t)LD * 4);
    float* sh     = (float*)alloc((size_t)LD * 4);
    float* gsum   = (float*)alloc((size_t)G * H2 * 4);
    int*   gstart = (int*)alloc((size_t)(G + 1) * 4);
    unsigned short* w1hi = (unsigned short*)alloc((size_t)LD * H1 * 2);
    unsigned short* w1lo = (unsigned short*)alloc((size_t)LD * H1 * 2);
    unsigned short* w2hi = (unsigned short*)alloc((size_t)H1 * H2 * 2);
    unsigned short* w2lo = (unsigned short*)alloc((size_t)H1 * H2 * 2);
    int2* part = (int2*)bufB;                    // dead before first k_conv
    unsigned short* xw = (unsigned short*)bufB;  // bf16 [N][64] message table
    unsigned short* h1b = (unsigned short*)bufB; // bf16 [N][256] after convs
    float* h2 = local;                           // fp32 [N][128]; local dead after enc1

    hipMemsetAsync(ghist, 0, (size_t)NBK * 4, stream);
    hipMemsetAsync(gsum, 0, (size_t)G * H2 * 4, stream);

    int nchunks = (E + 8191) / 8192;
    k_hist<<<nchunks, 256, NBK * 4, stream>>>(ei + E, ghist, E, NBK);
    k_bscan<<<1, 512, 0, stream>>>(ghist, bstart, gcur, offs, NBK, N, E);
    k_part<<<nchunks, 256, 2 * NBK * 4, stream>>>(ei, ei + E, gcur, part, E, NBK);
    k_bucket<<<NBK, 256, 0, stream>>>(part, bstart, offs, dis, csrc, N);
    k_gb<<<1, 128, 0, stream>>>(batch, gstart, N, G);
    k_bnprep<<<(LD + 255) / 256, 256, 0, stream>>>(convb, gamma, beta, mean, var, sc, sh, LD);
    k_wsplit<<<(LD * H1 + 255) / 256, 256, 0, stream>>>(eW1, w1hi, w1lo, LD, H1, 8);
    k_wsplit<<<(H1 * H2 + 255) / 256, 256, 0, stream>>>(eW2, w2hi, w2lo, H1, H2, 7);

    for (int l = 0; l < L; ++l) {
        const float* Ain = (l == 0) ? x : (local + (size_t)(l - 1) * D);
        int lda = (l == 0) ? D : LD;
        k_conv<<<(N + 63) / 64, 256, 0, stream>>>(Ain, lda, convW + (size_t)l * D * D, dis, xw, N);
        const float* skip = (l % 2 == 0 && l != 0 && l != L - 1) ? (local + (size_t)(l - 2) * D) : nullptr;
        k_agg<<<(N + 3) / 4, 256, 0, stream>>>(xw, offs, csrc, dis, sc + (size_t)l * D,
                                               sh + (size_t)l * D, skip,
                                               local + (size_t)l * D, LD,
                                               localb + (size_t)l * D, N);
    }

    // enc1: A = localb bf16 [N][256], out h1b bf16 [N][256]. WN=4 -> BM=32.
    k_encb<<<(N + 31) / 32, 256, 0, stream>>>(localb, N, LD, 4, w1hi, w1lo, eb1,
                                              h1b, nullptr, H1);
    // enc2: A = h1b bf16 [N][256], out h2 fp32 [N][128]. WN=2 -> BM=64.
    k_encb<<<(N + 63) / 64, 256, 0, stream>>>(h1b, N, H1, 2, w2hi, w2lo, eb2,
                                              nullptr, h2, H2);

    k_pool<<<G * SMAX, 256, 0, stream>>>(h2, gstart, gsum, H2);
    k_dec<<<G, HD, 0, stream>>>(gsum, gstart, dW1, db1, dW2, db2, (float*)d_out, H2, HD);
}

// Round 8
// 765.311 us; speedup vs baseline: 1.1171x; 1.1171x over previous
//
#include <hip/hip_runtime.h>
#include <cstdint>
#include <cstddef>

#define D 64
#define SMAX 24

typedef __attribute__((ext_vector_type(8))) short short8;
typedef __attribute__((ext_vector_type(4))) float floatx4;

__device__ inline unsigned short f2bf(float f) {   // RNE fp32 -> bf16
    unsigned u = __float_as_uint(f);
    unsigned r = 0x7FFFu + ((u >> 16) & 1u);
    return (unsigned short)((u + r) >> 16);
}
__device__ inline float bf2f(unsigned short h) {
    return __uint_as_float(((unsigned)h) << 16);
}

// ---------------- bucket-partition CSR build ----------------

__global__ void k_hist(const int* __restrict__ col, int* __restrict__ ghist,
                       int E, int NBK) {
    extern __shared__ int lh[];
    int t = threadIdx.x;
    for (int i = t; i < NBK; i += 256) lh[i] = 0;
    __syncthreads();
    int base = blockIdx.x * 8192;
    int end = base + 8192; if (end > E) end = E;
    for (int e = base + t; e < end; e += 256) atomicAdd(&lh[col[e] >> 8], 1);
    __syncthreads();
    for (int i = t; i < NBK; i += 256) if (lh[i]) atomicAdd(&ghist[i], lh[i]);
}

__global__ void k_bscan(const int* __restrict__ ghist, int* __restrict__ bstart,
                        int* __restrict__ gcur, int* __restrict__ offs,
                        int NBK, int N, int E) {
    __shared__ int s[512];
    int t = threadIdx.x;
    int v = (t < NBK) ? ghist[t] : 0;
    s[t] = v; __syncthreads();
    for (int off = 1; off < 512; off <<= 1) {
        int x = (t >= off) ? s[t - off] : 0;
        __syncthreads();
        s[t] += x;
        __syncthreads();
    }
    int excl = s[t] - v;
    if (t < NBK) { bstart[t] = excl; gcur[t] = excl; }
    if (t == 0) { bstart[NBK] = E; offs[N] = E; }
}

__global__ __launch_bounds__(256) void k_part(const int* __restrict__ row,
                                              const int* __restrict__ col,
                                              int* __restrict__ gcur,
                                              int2* __restrict__ part,
                                              int E, int NBK) {
    extern __shared__ int sm[];
    int* lcnt = sm;
    int* lbase = sm + NBK;
    int t = threadIdx.x;
    for (int i = t; i < NBK; i += 256) lcnt[i] = 0;
    __syncthreads();
    int base = blockIdx.x * 8192;
    int end = base + 8192; if (end > E) end = E;
    for (int e = base + t; e < end; e += 256) atomicAdd(&lcnt[col[e] >> 8], 1);
    __syncthreads();
    for (int i = t; i < NBK; i += 256) {
        int c = lcnt[i];
        lbase[i] = c ? atomicAdd(&gcur[i], c) : 0;
    }
    __syncthreads();
    for (int i = t; i < NBK; i += 256) lcnt[i] = 0;
    __syncthreads();
    for (int e = base + t; e < end; e += 256) {
        int c = col[e];
        int b = c >> 8;
        int p = lbase[b] + atomicAdd(&lcnt[b], 1);
        part[p] = make_int2(row[e], c);
    }
}

__global__ __launch_bounds__(256) void k_bucket(const int2* __restrict__ part,
                                                const int* __restrict__ bstart,
                                                int* __restrict__ offs,
                                                float* __restrict__ dis,
                                                int* __restrict__ csrc, int N) {
    __shared__ int ncnt[256];
    __shared__ int s[256];
    __shared__ int lcur[256];
    int b = blockIdx.x;
    int t = threadIdx.x;
    int n0 = b << 8;
    int e0 = bstart[b], e1 = bstart[b + 1];
    ncnt[t] = 0;
    __syncthreads();
    for (int e = e0 + t; e < e1; e += 256) {
        int2 pr = part[e];
        atomicAdd(&ncnt[pr.y & 255], 1);
    }
    __syncthreads();
    int v = ncnt[t];
    s[t] = v; __syncthreads();
    for (int off = 1; off < 256; off <<= 1) {
        int x = (t >= off) ? s[t - off] : 0;
        __syncthreads();
        s[t] += x;
        __syncthreads();
    }
    int excl = s[t] - v;
    int node = n0 + t;
    if (node < N) {
        offs[node] = e0 + excl;
        dis[node] = rsqrtf((float)(v + 1));
    }
    lcur[t] = excl;
    __syncthreads();
    for (int e = e0 + t; e < e1; e += 256) {
        int2 pr = part[e];
        int p = atomicAdd(&lcur[pr.y & 255], 1);
        csrc[e0 + p] = pr.x;
    }
}

// graph boundaries
__global__ void k_gb(const int* __restrict__ batch, int* __restrict__ gstart,
                     int N, int G) {
    int g = threadIdx.x;
    if (g > G) return;
    int lo = 0, hi = N;
    while (lo < hi) {
        int mid = (lo + hi) >> 1;
        if (batch[mid] < g) lo = mid + 1; else hi = mid;
    }
    gstart[g] = lo;
}

// fold BN (eval) + conv bias into per-channel scale/shift
__global__ void k_bnprep(const float* __restrict__ cb, const float* __restrict__ g,
                         const float* __restrict__ be, const float* __restrict__ mu,
                         const float* __restrict__ var, float* __restrict__ sc,
                         float* __restrict__ sh, int LD) {
    int i = blockIdx.x * 256 + threadIdx.x;
    if (i < LD) {
        float s = g[i] * rsqrtf(var[i] + 1e-5f);
        sc[i] = s;
        sh[i] = (cb[i] - mu[i]) * s + be[i];
    }
}

// split fp32 weights into bf16 hi/lo, packed in MFMA fragment order:
// element (k,n) -> chunk c=k/32, ntile=n/64, j=(n&63)>>4, lane=((k&31)>>3)*16+(n&15),
// kidx=k&7; flat = (((c*(Nc/64)+ntile)*4+j)*64 + lane)*8 + kidx.
// A wave's bh[j] load becomes lane-contiguous (1KB coalesced).
__global__ void k_wpack(const float* __restrict__ B, unsigned short* __restrict__ hiP,
                        unsigned short* __restrict__ loP, int K, int Nc, int nshift) {
    int idx = blockIdx.x * 256 + threadIdx.x;
    if (idx >= K * Nc) return;
    int k = idx >> nshift;
    int n = idx & (Nc - 1);
    float a = B[idx];
    unsigned b = __float_as_uint(a);
    unsigned hb = b & 0xFFFF0000u;
    float ah = __uint_as_float(hb);
    float al = a - ah;
    int c = k >> 5;
    int ntile = n >> 6;
    int j = (n & 63) >> 4;
    int lane = ((k & 31) >> 3) * 16 + (n & 15);
    int kidx = k & 7;
    size_t o = ((((size_t)c * (Nc >> 6) + ntile) * 4 + j) * 64 + lane) * 8 + kidx;
    hiP[o] = (unsigned short)(hb >> 16);
    loP[o] = (unsigned short)(__float_as_uint(al) >> 16);
}

// ---------------- conv GEMM: xw' = bf16((A @ W) * dis[row]),  K=D=64 ----------------

__global__ __launch_bounds__(256) void k_conv(const float* __restrict__ A, int lda,
                                              const float* __restrict__ W,
                                              const float* __restrict__ dis,
                                              unsigned short* __restrict__ out, int N) {
    __shared__ float At[64][68];
    __shared__ float Wl[64][64];
    int t = threadIdx.x;
    int bm = blockIdx.x * 64;
    {
        int row = t >> 2, kc = (t & 3) * 16;
        int r = bm + row;
        float v[16];
        if (r < N) {
            const float* p = A + (size_t)r * lda + kc;
#pragma unroll
            for (int j = 0; j < 16; j += 4) {
                float4 x = *(const float4*)(p + j);
                v[j] = x.x; v[j + 1] = x.y; v[j + 2] = x.z; v[j + 3] = x.w;
            }
        } else {
#pragma unroll
            for (int j = 0; j < 16; ++j) v[j] = 0.f;
        }
#pragma unroll
        for (int j = 0; j < 16; ++j) At[kc + j][row] = v[j];
        const float* wp = W + row * 64 + kc;
#pragma unroll
        for (int j = 0; j < 16; j += 4)
            *(float4*)&Wl[row][kc + j] = *(const float4*)(wp + j);
    }
    __syncthreads();
    int m0 = (t & 15) * 4, n0 = (t >> 4) * 4;
    float acc[4][4];
#pragma unroll
    for (int i = 0; i < 4; ++i)
#pragma unroll
        for (int j = 0; j < 4; ++j) acc[i][j] = 0.f;
#pragma unroll 8
    for (int kk = 0; kk < 64; ++kk) {
        float4 a = *(const float4*)&At[kk][m0];
        float4 b = *(const float4*)&Wl[kk][n0];
        float av[4] = {a.x, a.y, a.z, a.w};
        float bv[4] = {b.x, b.y, b.z, b.w};
#pragma unroll
        for (int i = 0; i < 4; ++i)
#pragma unroll
            for (int j = 0; j < 4; ++j) acc[i][j] = fmaf(av[i], bv[j], acc[i][j]);
    }
#pragma unroll
    for (int i = 0; i < 4; ++i) {
        int r = bm + m0 + i;
        if (r < N) {
            float dv = dis[r];
            ushort4 o;
            o.x = f2bf(acc[i][0] * dv);
            o.y = f2bf(acc[i][1] * dv);
            o.z = f2bf(acc[i][2] * dv);
            o.w = f2bf(acc[i][3] * dv);
            *(ushort4*)&out[(size_t)r * 64 + n0] = o;
        }
    }
}

// ---------------- aggregation: one node per wave, bf16 gathers; writes fp32 + bf16 ----------------

__global__ __launch_bounds__(256) void k_agg(const unsigned short* __restrict__ xw,
                                             const int* __restrict__ offs,
                                             const int* __restrict__ src,
                                             const float* __restrict__ dis,
                                             const float* __restrict__ sc,
                                             const float* __restrict__ sh,
                                             const float* __restrict__ skip,
                                             float* __restrict__ out,
                                             int ld,
                                             unsigned short* __restrict__ outb,
                                             int N) {
    int t = threadIdx.x;
    int lane = t & 63;
    int w = t >> 6;
    int v = blockIdx.x * 4 + w;
    if (v >= N) return;
    int es = lane >> 4;         // edge slot 0..3
    int f4 = lane & 15;         // 4-channel group
    int c0 = f4 * 4;
    const unsigned short* xp = xw + c0;
    float ax = 0.f, ay = 0.f, az = 0.f, aw_ = 0.f;
    int e0 = offs[v], e1 = offs[v + 1];
    int deg = e1 - e0;
    int k = 0;
    for (; k + 16 <= deg; k += 16) {
        int ld16 = (lane < 16) ? src[e0 + k + lane] : 0;
        int s0 = __shfl(ld16, es);
        int s1 = __shfl(ld16, es + 4);
        int s2 = __shfl(ld16, es + 8);
        int s3 = __shfl(ld16, es + 12);
        ushort4 m0 = *(const ushort4*)(xp + (size_t)s0 * 64);
        ushort4 m1 = *(const ushort4*)(xp + (size_t)s1 * 64);
        ushort4 m2 = *(const ushort4*)(xp + (size_t)s2 * 64);
        ushort4 m3 = *(const ushort4*)(xp + (size_t)s3 * 64);
        ax += (bf2f(m0.x) + bf2f(m1.x)) + (bf2f(m2.x) + bf2f(m3.x));
        ay += (bf2f(m0.y) + bf2f(m1.y)) + (bf2f(m2.y) + bf2f(m3.y));
        az += (bf2f(m0.z) + bf2f(m1.z)) + (bf2f(m2.z) + bf2f(m3.z));
        aw_ += (bf2f(m0.w) + bf2f(m1.w)) + (bf2f(m2.w) + bf2f(m3.w));
    }
    for (; k + 4 <= deg; k += 4) {
        int ld4 = (lane < 4) ? src[e0 + k + lane] : 0;
        int s0 = __shfl(ld4, es);
        ushort4 m0 = *(const ushort4*)(xp + (size_t)s0 * 64);
        ax += bf2f(m0.x); ay += bf2f(m0.y); az += bf2f(m0.z); aw_ += bf2f(m0.w);
    }
    int rem = deg - k;
    if (es < rem) {
        int s0 = src[e0 + k + es];
        ushort4 m0 = *(const ushort4*)(xp + (size_t)s0 * 64);
        ax += bf2f(m0.x); ay += bf2f(m0.y); az += bf2f(m0.z); aw_ += bf2f(m0.w);
    }
    ax += __shfl_xor(ax, 16); ay += __shfl_xor(ay, 16);
    az += __shfl_xor(az, 16); aw_ += __shfl_xor(aw_, 16);
    ax += __shfl_xor(ax, 32); ay += __shfl_xor(ay, 32);
    az += __shfl_xor(az, 32); aw_ += __shfl_xor(aw_, 32);
    if (es == 0) {
        ushort4 a = *(const ushort4*)(xp + (size_t)v * 64);   // self loop
        ax += bf2f(a.x); ay += bf2f(a.y); az += bf2f(a.z); aw_ += bf2f(a.w);
        float dv = dis[v];
        float4 S = *(const float4*)&sc[c0];
        float4 H = *(const float4*)&sh[c0];
        float y0 = fmaxf(fmaf(ax * dv, S.x, H.x), 0.f);
        float y1 = fmaxf(fmaf(ay * dv, S.y, H.y), 0.f);
        float y2 = fmaxf(fmaf(az * dv, S.z, H.z), 0.f);
        float y3 = fmaxf(fmaf(aw_ * dv, S.w, H.w), 0.f);
        size_t ob = (size_t)v * ld + c0;
        if (skip) {
            const float4 s4 = *(const float4*)(skip + ob);
            y0 += s4.x; y1 += s4.y; y2 += s4.z; y3 += s4.w;
        }
        float4 o; o.x = y0; o.y = y1; o.z = y2; o.w = y3;
        *(float4*)(out + ob) = o;
        ushort4 ob4;
        ob4.x = f2bf(y0); ob4.y = f2bf(y1); ob4.z = f2bf(y2); ob4.w = f2bf(y3);
        *(ushort4*)(outb + ob) = ob4;
    }
}

// ---------------- encoder GEMM: barrier-free, coalesced packed B, SW-pipelined ----------------
// C = relu(A @ (Bhi+Blo) + bias). Wave tile m=32 x n=64. WN waves across n.
// B pre-packed in fragment order (k_wpack) -> 1KB coalesced loads.
// Explicit double-buffered fragment registers keep ~10 loads in flight.

__global__ __launch_bounds__(256) void k_encb(const unsigned short* __restrict__ A,
                                              int M, int K, int WN,
                                              const unsigned short* __restrict__ BhiP,
                                              const unsigned short* __restrict__ BloP,
                                              const float* __restrict__ bias,
                                              unsigned short* __restrict__ Cb,
                                              float* __restrict__ Cf, int ldc) {
    int t = threadIdx.x;
    int lane = t & 63;
    int l16 = lane & 15;
    int quad = lane >> 4;
    int w = t >> 6;
    int nw = w % WN;
    int mg = w / WN;
    int BM = 32 * (4 / WN);
    int bm = blockIdx.x * BM + mg * 32;
    int n0 = nw * 64;
    int NC = K >> 5;                       // K-chunks
    size_t cstr = (size_t)(ldc >> 6) * 2048;  // ushorts per chunk

    floatx4 acc[2][4];
#pragma unroll
    for (int i = 0; i < 2; ++i)
#pragma unroll
        for (int j = 0; j < 4; ++j) acc[i][j] = (floatx4)0.f;

    int m0 = bm + l16, m1 = bm + 16 + l16;
    bool v0 = m0 < M, v1 = m1 < M;
    const unsigned short* a0 = A + (size_t)(v0 ? m0 : 0) * K + quad * 8;
    const unsigned short* a1 = A + (size_t)(v1 ? m1 : 0) * K + quad * 8;
    const unsigned short* bp = BhiP + ((size_t)(n0 >> 6) * 4) * 512 + lane * 8;
    size_t loOff = (size_t)(BloP - BhiP);

    // prologue: chunk 0 fragments
    short8 a0c = *(const short8*)a0;
    short8 a1c = *(const short8*)a1;
    short8 bhc[4], blc[4];
#pragma unroll
    for (int j = 0; j < 4; ++j) {
        bhc[j] = *(const short8*)(bp + j * 512);
        blc[j] = *(const short8*)(bp + loOff + j * 512);
    }

    for (int c = 0; c < NC; ++c) {
        short8 a0n, a1n, bhn[4], bln[4];
        if (c + 1 < NC) {
            a0n = *(const short8*)(a0 + (c + 1) * 32);
            a1n = *(const short8*)(a1 + (c + 1) * 32);
            const unsigned short* bpn = bp + (size_t)(c + 1) * cstr;
#pragma unroll
            for (int j = 0; j < 4; ++j) {
                bhn[j] = *(const short8*)(bpn + j * 512);
                bln[j] = *(const short8*)(bpn + loOff + j * 512);
            }
        }
#pragma unroll
        for (int j = 0; j < 4; ++j) {
            acc[0][j] = __builtin_amdgcn_mfma_f32_16x16x32_bf16(a0c, blc[j], acc[0][j], 0, 0, 0);
            acc[0][j] = __builtin_amdgcn_mfma_f32_16x16x32_bf16(a0c, bhc[j], acc[0][j], 0, 0, 0);
            acc[1][j] = __builtin_amdgcn_mfma_f32_16x16x32_bf16(a1c, blc[j], acc[1][j], 0, 0, 0);
            acc[1][j] = __builtin_amdgcn_mfma_f32_16x16x32_bf16(a1c, bhc[j], acc[1][j], 0, 0, 0);
        }
        a0c = a0n; a1c = a1n;
#pragma unroll
        for (int j = 0; j < 4; ++j) { bhc[j] = bhn[j]; blc[j] = bln[j]; }
    }

#pragma unroll
    for (int i = 0; i < 2; ++i) {
#pragma unroll
        for (int r = 0; r < 4; ++r) {
            int m = bm + i * 16 + quad * 4 + r;
            if (m < M) {
#pragma unroll
                for (int j = 0; j < 4; ++j) {
                    float y = fmaxf(acc[i][j][r] + bias[n0 + j * 16 + l16], 0.f);
                    size_t idx = (size_t)m * ldc + n0 + j * 16 + l16;
                    if (Cb) Cb[idx] = f2bf(y);
                    else    Cf[idx] = y;
                }
            }
        }
    }
}

// ---------------- graph mean-pool ----------------

__global__ __launch_bounds__(256) void k_pool(const float* __restrict__ h2,
                                              const int* __restrict__ gstart,
                                              float* __restrict__ gsum, int H) {
    int g = blockIdx.x / SMAX;
    int s = blockIdx.x % SMAX;
    int base = gstart[g], end = gstart[g + 1];
    int cnt = end - base;
    if (cnt <= 0) return;
    int per = (cnt + SMAX - 1) / SMAX;
    int n0 = base + s * per;
    int n1 = n0 + per; if (n1 > end) n1 = end;
    if (n0 >= n1) return;
    int t = threadIdx.x;
    int q = t & 31;
    int c = q * 4;
    int sub = t >> 5;
    float4 acc = make_float4(0.f, 0.f, 0.f, 0.f);
    for (int n = n0 + sub; n < n1; n += 8) {
        float4 v = *(const float4*)(h2 + (size_t)n * H + c);
        acc.x += v.x; acc.y += v.y; acc.z += v.z; acc.w += v.w;
    }
    __shared__ float4 red[8][32];
    red[sub][q] = acc;
    __syncthreads();
    if (sub == 0) {
        float4 a = red[0][q];
#pragma unroll
        for (int i = 1; i < 8; ++i) {
            float4 b = red[i][q];
            a.x += b.x; a.y += b.y; a.z += b.z; a.w += b.w;
        }
        atomicAdd(&gsum[(size_t)g * H + c + 0], a.x);
        atomicAdd(&gsum[(size_t)g * H + c + 1], a.y);
        atomicAdd(&gsum[(size_t)g * H + c + 2], a.z);
        atomicAdd(&gsum[(size_t)g * H + c + 3], a.w);
    }
}

// ---------------- decoder ----------------

__global__ void k_dec(const float* __restrict__ gsum, const int* __restrict__ gstart,
                      const float* __restrict__ W1, const float* __restrict__ b1,
                      const float* __restrict__ W2, const float* __restrict__ b2,
                      float* __restrict__ out, int H, int HD) {
    int g = blockIdx.x;
    int t = threadIdx.x;
    float cnt = (float)(gstart[g + 1] - gstart[g]);
    float inv = 1.0f / fmaxf(cnt, 1.0f);
    float hid = b1[t];
    for (int k = 0; k < H; ++k) {
        float gf = gsum[(size_t)g * H + k] * inv;
        hid = fmaf(gf, W1[k * HD + t], hid);
    }
    hid = fmaxf(hid, 0.f);
    float p = hid * W2[t];
    for (int off = 32; off > 0; off >>= 1) p += __shfl_down(p, off);
    if (t == 0) out[g] = p + b2[0];
}

// ---------------- host ----------------

extern "C" void kernel_launch(void* const* d_in, const int* in_sizes, int n_in,
                              void* d_out, int out_size, void* d_ws, size_t ws_size,
                              hipStream_t stream) {
    const float* x     = (const float*)d_in[0];
    const int*   ei    = (const int*)d_in[1];
    const int*   batch = (const int*)d_in[2];
    const float* convW = (const float*)d_in[3];
    const float* convb = (const float*)d_in[4];
    const float* gamma = (const float*)d_in[5];
    const float* beta  = (const float*)d_in[6];
    const float* mean  = (const float*)d_in[7];
    const float* var   = (const float*)d_in[8];
    const float* eW1   = (const float*)d_in[9];
    const float* eb1   = (const float*)d_in[10];
    const float* eW2   = (const float*)d_in[11];
    const float* eb2   = (const float*)d_in[12];
    const float* dW1   = (const float*)d_in[13];
    const float* db1   = (const float*)d_in[14];
    const float* dW2   = (const float*)d_in[15];
    const float* db2   = (const float*)d_in[16];

    int N  = in_sizes[0] / D;
    int E  = in_sizes[1] / 2;
    int L  = in_sizes[3] / (D * D);
    int G  = out_size;
    int LD = L * D;                 // 256
    int H1 = in_sizes[10];          // 256
    int H2 = in_sizes[12];          // 128
    int HD = in_sizes[14];          // 64
    int NBK = (N + 255) >> 8;       // 391

    char* ws = (char*)d_ws;
    size_t off = 0;
    auto alloc = [&](size_t b) -> void* {
        void* p = ws + off;
        off += (b + 255) & ~(size_t)255;
        return p;
    };
    float* local  = (float*)alloc((size_t)N * LD * 4);        // fp32 layer outputs; later h2
    unsigned short* localb = (unsigned short*)alloc((size_t)N * LD * 2);  // bf16 encoder-A copy
    char*  bufB   = (char*)alloc((size_t)N * LD * 2);         // part / xw / h1b
    int*   csrc   = (int*)alloc((size_t)E * 4);
    float* dis    = (float*)alloc((size_t)N * 4);
    int*   offs   = (int*)alloc((size_t)(N + 1) * 4);
    int*   ghist  = (int*)alloc((size_t)NBK * 4);
    int*   bstart = (int*)alloc((size_t)(NBK + 1) * 4);
    int*   gcur   = (int*)alloc((size_t)NBK * 4);
    float* sc     = (float*)alloc((size_t)LD * 4);
    float* sh     = (float*)alloc((size_t)LD * 4);
    float* gsum   = (float*)alloc((size_t)G * H2 * 4);
    int*   gstart = (int*)alloc((size_t)(G + 1) * 4);
    unsigned short* w1hi = (unsigned short*)alloc((size_t)LD * H1 * 2);
    unsigned short* w1lo = (unsigned short*)alloc((size_t)LD * H1 * 2);
    unsigned short* w2hi = (unsigned short*)alloc((size_t)H1 * H2 * 2);
    unsigned short* w2lo = (unsigned short*)alloc((size_t)H1 * H2 * 2);
    int2* part = (int2*)bufB;                    // dead before first k_conv
    unsigned short* xw = (unsigned short*)bufB;  // bf16 [N][64] message table
    unsigned short* h1b = (unsigned short*)bufB; // bf16 [N][256] after convs
    float* h2 = local;                           // fp32 [N][128]; local dead after enc1

    hipMemsetAsync(ghist, 0, (size_t)NBK * 4, stream);
    hipMemsetAsync(gsum, 0, (size_t)G * H2 * 4, stream);

    int nchunks = (E + 8191) / 8192;
    k_hist<<<nchunks, 256, NBK * 4, stream>>>(ei + E, ghist, E, NBK);
    k_bscan<<<1, 512, 0, stream>>>(ghist, bstart, gcur, offs, NBK, N, E);
    k_part<<<nchunks, 256, 2 * NBK * 4, stream>>>(ei, ei + E, gcur, part, E, NBK);
    k_bucket<<<NBK, 256, 0, stream>>>(part, bstart, offs, dis, csrc, N);
    k_gb<<<1, 128, 0, stream>>>(batch, gstart, N, G);
    k_bnprep<<<(LD + 255) / 256, 256, 0, stream>>>(convb, gamma, beta, mean, var, sc, sh, LD);
    k_wpack<<<(LD * H1 + 255) / 256, 256, 0, stream>>>(eW1, w1hi, w1lo, LD, H1, 8);
    k_wpack<<<(H1 * H2 + 255) / 256, 256, 0, stream>>>(eW2, w2hi, w2lo, H1, H2, 7);

    for (int l = 0; l < L; ++l) {
        const float* Ain = (l == 0) ? x : (local + (size_t)(l - 1) * D);
        int lda = (l == 0) ? D : LD;
        k_conv<<<(N + 63) / 64, 256, 0, stream>>>(Ain, lda, convW + (size_t)l * D * D, dis, xw, N);
        const float* skip = (l % 2 == 0 && l != 0 && l != L - 1) ? (local + (size_t)(l - 2) * D) : nullptr;
        k_agg<<<(N + 3) / 4, 256, 0, stream>>>(xw, offs, csrc, dis, sc + (size_t)l * D,
                                               sh + (size_t)l * D, skip,
                                               local + (size_t)l * D, LD,
                                               localb + (size_t)l * D, N);
    }

    // enc1: A = localb bf16 [N][256] -> h1b bf16 [N][256]. WN=4 -> BM=32.
    k_encb<<<(N + 31) / 32, 256, 0, stream>>>(localb, N, LD, 4, w1hi, w1lo, eb1,
                                              h1b, nullptr, H1);
    // enc2: A = h1b -> h2 fp32 [N][128]. WN=2 -> BM=64.
    k_encb<<<(N + 63) / 64, 256, 0, stream>>>(h1b, N, H1, 2, w2hi, w2lo, eb2,
                                              nullptr, h2, H2);

    k_pool<<<G * SMAX, 256, 0, stream>>>(h2, gstart, gsum, H2);
    k_dec<<<G, HD, 0, stream>>>(gsum, gstart, dW1, db1, dW2, db2, (float*)d_out, H2, HD);
}